// Round 11
// baseline (72.664 us; speedup 1.0000x reference)
//
#include <hip/hip_runtime.h>
#include <cstdint>

// Problem constants (from reference): B=4, Z=32, Y=512, X=512, R=1, C=16
static constexpr int Z_ = 32, Y_ = 512, X_ = 512;
static constexpr int ROW_WORDS = X_ / 32;                  // 16 u32 words per (b,z,y) row
static constexpr size_t NVOX = 4ull * Z_ * Y_ * X_;        // 33,554,432 voxels (2^25)
static constexpr size_t BITMAP_WORDS = NVOX / 32;          // 1M words = 4 MiB
static constexpr size_t BITMAP_BYTES = BITMAP_WORDS * 4;
static constexpr size_t BITMAP_OFF = 65536;                // counter+partials live below
static constexpr size_t RECORDS_OFF = BITMAP_OFF + BITMAP_BYTES;
static constexpr uint32_t REC_SENTINEL = 0xFFFFFFFFu;      // packed < 2^26, so invalid

// ws layout:
//   [0, 4)            : completion counter (zeroed each call by K1)
//   [64, 64+16*NBLK)  : per-block loss partials (float4: occ, off, feat, cnt)
//                       every slot written before read -> no init needed
//   [64KiB, +4MiB)    : RADAR occupancy bitmap (1 bit per voxel)
//   [.., +128MiB)     : records, DIRECT-MAPPED u32 per voxel:
//                       (dL1<<24)|(k<<19)|lidar_row ; REC_SENTINEL = no match.
//                       Only preset at radar voxels; never-preset voxels are
//                       never read -> no global init needed.
//
// Lessons encoded here:
//  - R9: cooperative grid.sync() ~190us/barrier on MI355X (cross-XCD spin);
//    phase separation by in-stream dispatch is ~50x cheaper.
//  - R4-R6: every scattered memory-side op (atomic or store) costs ~56B of
//    write traffic at ~0.8-1 TB/s regardless of target footprint; minimize
//    OP COUNT, not footprint.
//  - R7: rocclr fillBufferAligned runs at 8% occupancy; custom init kernel.

// K1: zero bitmap + counter, preset records at radar voxels (fire-and-forget
// NT stores; overlaps the streaming zero inside one dispatch).
__global__ __launch_bounds__(256) void init_preset(
        const int* __restrict__ radar_idx, int Nr,
        uint4* __restrict__ bitmap_v4, uint32_t n_bm4,
        uint32_t* __restrict__ records,
        uint32_t* __restrict__ counter) {
    uint32_t t = blockIdx.x * blockDim.x + threadIdx.x;
    uint32_t stride = gridDim.x * blockDim.x;
    if (t == 0) *counter = 0;
    const uint4 z = make_uint4(0u, 0u, 0u, 0u);
    for (uint32_t i = t; i < n_bm4; i += stride) bitmap_v4[i] = z;
    for (uint32_t i = t; i < (uint32_t)Nr; i += stride) {
        int4 ri = reinterpret_cast<const int4*>(radar_idx)[i];
        uint32_t key = (uint32_t)(((ri.x * Z_ + ri.y) * Y_ + ri.z) * X_ + ri.w);
        __builtin_nontemporal_store(REC_SENTINEL, &records[key]);  // idempotent preset
    }
}

// K2: radar presence bits (needs K1's zeroed bitmap).
__global__ void radar_bits(const int* __restrict__ radar_idx, int Nr,
                           uint32_t* __restrict__ bitmap) {
    int i = blockIdx.x * blockDim.x + threadIdx.x;
    if (i >= Nr) return;
    int4 ri = reinterpret_cast<const int4*>(radar_idx)[i];
    uint32_t key = (uint32_t)(((ri.x * Z_ + ri.y) * Y_ + ri.z) * X_ + ri.w);
    atomicOr(&bitmap[key >> 5], 1u << (key & 31));
}

// K3: lidar pass — strict in-domain 27-window over the radar bitmap, then
// direct atomicMin into records[vkey]. k = 26 - m maps the lidar-centered
// window index m to the radar-centered offset index of delta = L - R.
// Lexicographic min over (dL1, k, row) == reference first-occurrence argmin
// + min-lidar-row duplicate rule.
__global__ __launch_bounds__(256) void lidar_pass(
        const int* __restrict__ lidar_idx, int Nl,
        const uint32_t* __restrict__ bitmap,
        uint32_t* __restrict__ records) {
    int i = blockIdx.x * blockDim.x + threadIdx.x;
    if (i >= Nl) return;
    int4 li = reinterpret_cast<const int4*>(lidar_idx)[i];
    const int b = li.x, z = li.y, y = li.z, x = li.w;

    const int xm1 = max(x - 1, 0);
    const int w0  = xm1 >> 5;
    const int w1  = min(w0 + 1, ROW_WORDS - 1);
    const int base = w0 << 5;

    uint32_t mask = 0;  // bit m set => radar voxel present at window offset m
    #pragma unroll
    for (int dz = -1; dz <= 1; ++dz) {
        int zz = z + dz;
        if (zz < 0 || zz >= Z_) continue;
        #pragma unroll
        for (int dy = -1; dy <= 1; ++dy) {
            int yy = y + dy;
            if (yy < 0 || yy >= Y_) continue;
            uint32_t rw = (uint32_t)((b * Z_ + zz) * Y_ + yy) * ROW_WORDS;
            uint64_t win = (uint64_t)bitmap[rw + w0] |
                           ((uint64_t)bitmap[rw + w1] << 32);
            #pragma unroll
            for (int dx = -1; dx <= 1; ++dx) {
                int xx = x + dx;
                if (xx < 0 || xx >= X_) continue;
                int m = (dz + 1) * 9 + (dy + 1) * 3 + (dx + 1);
                mask |= (uint32_t)((win >> (xx - base)) & 1ull) << m;
            }
        }
    }

    while (mask) {
        int m = __builtin_ctz(mask);
        mask &= mask - 1;
        int mdz = m / 9 - 1, mr = m % 9;
        int mdy = mr / 3 - 1, mdx = mr % 3 - 1;
        uint32_t vkey = (uint32_t)(((b * Z_ + (z + mdz)) * Y_ + (y + mdy)) * X_ + (x + mdx));
        uint32_t dl1 = (uint32_t)(abs(mdz) + abs(mdy) + abs(mdx));
        uint32_t k   = (uint32_t)(26 - m);               // k of delta = L - R
        uint32_t packed = (dl1 << 24) | (k << 19) | (uint32_t)i;
        atomicMin(&records[vkey], packed);               // direct-mapped, no probe
    }
}

// K4: loss + fused finalize. Per-block partials (plain stores, bit-exact
// deterministic), completion counter, last block reduces partials via
// AGENT-scope atomic loads (cross-XCD safe: per-XCD L2s are not coherent,
// plain loads could see stale lines) and writes the scalar output.
__global__ __launch_bounds__(256) void loss_final(
        const float* __restrict__ pred_feat,
        const float* __restrict__ pred_occ,
        const float* __restrict__ lidar_feat,
        const int* __restrict__ radar_idx,
        const uint32_t* __restrict__ records,
        int Nr, int nblocks,
        float4* __restrict__ partials,
        uint32_t* __restrict__ counter,
        float* __restrict__ out) {
    float occ_a = 0.f, off_a = 0.f, feat_a = 0.f, cnt_a = 0.f;
    int r = blockIdx.x * blockDim.x + threadIdx.x;
    if (r < Nr) {
        int4 ri = reinterpret_cast<const int4*>(radar_idx)[r];
        uint32_t key = (uint32_t)(((ri.x * Z_ + ri.y) * Y_ + ri.z) * X_ + ri.w);
        uint32_t rec = records[key];     // preset in K1, maybe min'd in K3

        float o = pred_occ[r];
        float sp = fmaxf(o, 0.f) + log1pf(expf(-fabsf(o)));  // stable softplus
        bool matched = (rec != REC_SENTINEL);
        occ_a = sp - (matched ? o : 0.f);

        if (matched) {
            cnt_a = 1.f;
            int wk  = (int)((rec >> 19) & 31u);
            int row = (int)(rec & 0x7FFFFu);
            int wdz = wk / 9 - 1, wr = wk % 9;
            int wdy = wr / 3 - 1, wdx = wr % 3 - 1;
            float4 pf = reinterpret_cast<const float4*>(pred_feat)[r];
            float p[3]  = { pf.x, pf.y, pf.z };
            float gt[3] = { (float)wdz, (float)wdy, (float)wdx };
            #pragma unroll
            for (int j = 0; j < 3; ++j) {
                float dd = p[j] - gt[j];
                float ad = fabsf(dd);
                off_a += (ad < 1.f) ? 0.5f * dd * dd : ad - 0.5f;
            }
            feat_a = fabsf(pf.w - lidar_feat[16 * row]);
        }
    }

    // wave-64 butterfly + LDS block reduce
    #pragma unroll
    for (int o = 32; o >= 1; o >>= 1) {
        occ_a  += __shfl_xor(occ_a,  o, 64);
        off_a  += __shfl_xor(off_a,  o, 64);
        feat_a += __shfl_xor(feat_a, o, 64);
        cnt_a  += __shfl_xor(cnt_a,  o, 64);
    }
    __shared__ float red[4][4];
    __shared__ bool last;
    int wid = threadIdx.x >> 6;
    if ((threadIdx.x & 63) == 0) {
        red[wid][0] = occ_a; red[wid][1] = off_a;
        red[wid][2] = feat_a; red[wid][3] = cnt_a;
    }
    __syncthreads();
    if (threadIdx.x == 0) {
        float s0 = 0.f, s1 = 0.f, s2 = 0.f, s3 = 0.f;
        #pragma unroll
        for (int w = 0; w < 4; ++w) {
            s0 += red[w][0]; s1 += red[w][1]; s2 += red[w][2]; s3 += red[w][3];
        }
        partials[blockIdx.x] = make_float4(s0, s1, s2, s3);
        __threadfence();                       // publish partial before counting
        uint32_t prev = atomicAdd(counter, 1u);
        last = (prev == (uint32_t)(nblocks - 1));
    }
    __syncthreads();
    if (last) {
        __threadfence();                       // acquire side
        float t0 = 0.f, t1 = 0.f, t2 = 0.f, t3 = 0.f;
        for (int i = threadIdx.x; i < nblocks; i += 256) {
            const float* p = reinterpret_cast<const float*>(&partials[i]);
            t0 += __hip_atomic_load(p + 0, __ATOMIC_RELAXED, __HIP_MEMORY_SCOPE_AGENT);
            t1 += __hip_atomic_load(p + 1, __ATOMIC_RELAXED, __HIP_MEMORY_SCOPE_AGENT);
            t2 += __hip_atomic_load(p + 2, __ATOMIC_RELAXED, __HIP_MEMORY_SCOPE_AGENT);
            t3 += __hip_atomic_load(p + 3, __ATOMIC_RELAXED, __HIP_MEMORY_SCOPE_AGENT);
        }
        #pragma unroll
        for (int o = 32; o >= 1; o >>= 1) {
            t0 += __shfl_xor(t0, o, 64);
            t1 += __shfl_xor(t1, o, 64);
            t2 += __shfl_xor(t2, o, 64);
            t3 += __shfl_xor(t3, o, 64);
        }
        __syncthreads();                       // red[] reuse is safe after this
        if ((threadIdx.x & 63) == 0) {
            red[wid][0] = t0; red[wid][1] = t1;
            red[wid][2] = t2; red[wid][3] = t3;
        }
        __syncthreads();
        if (threadIdx.x == 0) {
            float s0 = 0.f, s1 = 0.f, s2 = 0.f, s3 = 0.f;
            #pragma unroll
            for (int w = 0; w < 4; ++w) {
                s0 += red[w][0]; s1 += red[w][1]; s2 += red[w][2]; s3 += red[w][3];
            }
            float occ  = s0 / (float)Nr;
            float cnt  = s3;
            float offl = s1 / fmaxf(cnt * 3.f, 1.f);
            float feat = s2 / fmaxf(cnt, 1.f);
            out[0] = 0.2f * occ + offl + feat;
        }
    }
}

extern "C" void kernel_launch(void* const* d_in, const int* in_sizes, int n_in,
                              void* d_out, int out_size, void* d_ws, size_t ws_size,
                              hipStream_t stream) {
    const float* pred_feat  = (const float*)d_in[0];
    const float* pred_occ   = (const float*)d_in[1];
    const float* lidar_feat = (const float*)d_in[2];
    const int*   radar_idx  = (const int*)d_in[3];
    const int*   lidar_idx  = (const int*)d_in[4];
    int Nr = in_sizes[1];        // pred_occ is (Nr, 1)
    int Nl = in_sizes[2] / 16;   // lidar_features is (Nl, 16)

    uint32_t* counter  = (uint32_t*)d_ws;
    float4*   partials = (float4*)((char*)d_ws + 64);
    uint32_t* bitmap   = (uint32_t*)((char*)d_ws + BITMAP_OFF);
    uint32_t* records  = (uint32_t*)((char*)d_ws + RECORDS_OFF);  // 128 MiB direct map

    const uint32_t n_bm4 = (uint32_t)(BITMAP_BYTES / 16);
    const int nblocks = (Nr + 255) / 256;

    hipLaunchKernelGGL(init_preset, dim3(1024), dim3(256), 0, stream,
                       radar_idx, Nr, (uint4*)bitmap, n_bm4, records, counter);
    hipLaunchKernelGGL(radar_bits, dim3(nblocks), dim3(256), 0, stream,
                       radar_idx, Nr, bitmap);
    hipLaunchKernelGGL(lidar_pass, dim3((Nl + 255) / 256), dim3(256), 0, stream,
                       lidar_idx, Nl, bitmap, records);
    hipLaunchKernelGGL(loss_final, dim3(nblocks), dim3(256), 0, stream,
                       pred_feat, pred_occ, lidar_feat, radar_idx, records,
                       Nr, nblocks, partials, counter, (float*)d_out);
}